// Round 13
// baseline (108.044 us; speedup 1.0000x reference)
//
#include <hip/hip_runtime.h>
#include <hip/hip_bf16.h>
#include <math.h>

// Problem constants
#define B_ROWS 4096
#define N_ROWS 8192          // 2B
#define D_DIM  1024
#define NTILES 64            // 8192 / 128
#define NSLOT  64            // partial slots per row = one per "other" tile
#define NPAIRS (NTILES * (NTILES + 1) / 2)  // 2080 upper-triangle tile pairs
#define NXCD 8

#define BM 128
#define BK 64                // i8 elems per K-tile = 64 B per row
#define NT (D_DIM / BK)      // 16 K-tiles
#define SLOT_BYTES 8192      // A only per ring slot (B is global-direct)
#define RING 2               // double buffer: 16 KB LDS

typedef __attribute__((ext_vector_type(4))) int i32x4;

__device__ __forceinline__ void load_lds_16B(const void* g, void* l) {
  __builtin_amdgcn_global_load_lds(
      (const __attribute__((address_space(1))) void*)g,
      (__attribute__((address_space(3))) void*)l, 16, 0, 0);
}

#define VMCNT0() asm volatile("s_waitcnt vmcnt(0)" ::: "memory")
#define LGKM0()  asm volatile("s_waitcnt lgkmcnt(0)" ::: "memory")
#define BARRIER() asm volatile("s_barrier" ::: "memory")

// ---------------------------------------------------------------------------
// Kernel 1: wave-per-row L2-normalize + symmetric int8 quantization.
// ---------------------------------------------------------------------------
__global__ __launch_bounds__(256) void normalize_kernel(
    const float* __restrict__ emb_i, const float* __restrict__ emb_j,
    char* __restrict__ zq, float* __restrict__ rowS) {
  const int lane = threadIdx.x & 63;
  const int wave = threadIdx.x >> 6;
  const int row = blockIdx.x * 4 + wave;
  const float* src = (row < B_ROWS) ? (emb_i + (size_t)row * D_DIM)
                                    : (emb_j + (size_t)(row - B_ROWS) * D_DIM);
  const float4* s4 = reinterpret_cast<const float4*>(src);
  float4 v0 = s4[lane], v1 = s4[lane + 64], v2 = s4[lane + 128],
         v3 = s4[lane + 192];

  float ss = v0.x * v0.x + v0.y * v0.y + v0.z * v0.z + v0.w * v0.w +
             v1.x * v1.x + v1.y * v1.y + v1.z * v1.z + v1.w * v1.w +
             v2.x * v2.x + v2.y * v2.y + v2.z * v2.z + v2.w * v2.w +
             v3.x * v3.x + v3.y * v3.y + v3.z * v3.z + v3.w * v3.w;
#pragma unroll
  for (int m = 32; m; m >>= 1) ss += __shfl_xor(ss, m, 64);
  const float scale = 1.0f / fmaxf(sqrtf(ss), 1e-12f);

  float z[16];
  z[0] = v0.x * scale;  z[1] = v0.y * scale;  z[2] = v0.z * scale;
  z[3] = v0.w * scale;  z[4] = v1.x * scale;  z[5] = v1.y * scale;
  z[6] = v1.z * scale;  z[7] = v1.w * scale;  z[8] = v2.x * scale;
  z[9] = v2.y * scale;  z[10] = v2.z * scale; z[11] = v2.w * scale;
  z[12] = v3.x * scale; z[13] = v3.y * scale; z[14] = v3.z * scale;
  z[15] = v3.w * scale;

  float am = 0.0f;
#pragma unroll
  for (int i = 0; i < 16; ++i) am = fmaxf(am, fabsf(z[i]));
#pragma unroll
  for (int m = 32; m; m >>= 1) am = fmaxf(am, __shfl_xor(am, m, 64));
  const float s = am * (1.0f / 127.0f);
  const float inv = (am > 0.0f) ? 127.0f / am : 0.0f;

  char4* dst = reinterpret_cast<char4*>(zq + (size_t)row * D_DIM);
#pragma unroll
  for (int i = 0; i < 4; ++i) {
    char4 pk;
    pk.x = (char)(int)rintf(z[i * 4 + 0] * inv);
    pk.y = (char)(int)rintf(z[i * 4 + 1] * inv);
    pk.z = (char)(int)rintf(z[i * 4 + 2] * inv);
    pk.w = (char)(int)rintf(z[i * 4 + 3] * inv);
    dst[lane + 64 * i] = pk;
  }
  if (lane == 0) rowS[row] = s;
}

// ---------------------------------------------------------------------------
// Kernel 2: fused i8 GEMM + scale + exp + row/col-sum, symmetric tile pairs.
// R8 ring-2 schedule, but LDS holds ONLY the A panel; B fragments are loaded
// global->reg per lane (z is L2/L3-resident; wr-partner wave re-reads the
// same B addresses -> L1 hits). Halves LDS traffic per block K-tile
// (48 -> 24 KB); the global path runs on a separate pipe.
// MfmaUtil model (validated R8): util ~= MFMA_cyc / LDS_cyc.
//
// MFMA = mfma_i32_16x16x64_i8 (4-reg C/D -> AGPR; 16-reg C/D spills).
// LDS per ring slot (8 KB): A[128][64B]. Row r: 4 16-B slots; logical slot s
// at physical s ^ ((r>>1)&3) (pre-swizzled global source + swizzled ds_read;
// measured 0 conflicts). B direct: row m0 + wc*64 + ni*16 + l15, 16 B at
// kk*64 + l4*16 (same logical k-chunk l4 as A -> permutation cancels).
// C/D (16x16, dtype-independent): col = lane&15, row = (l>>4)*4 + reg.
// ---------------------------------------------------------------------------
__global__ __launch_bounds__(256, 3) void simexp_kernel(
    const char* __restrict__ zq, const float* __restrict__ rowS,
    float* __restrict__ partial, float* __restrict__ dn,
    float* __restrict__ pos) {
  __shared__ __align__(16) char ldsbuf[RING * SLOT_BYTES];  // 16 KB
  __shared__ float rowAcc[BM];
  __shared__ float colAcc[BM];
  __shared__ float sRow[BM];
  __shared__ float sCol[BM];

  const int tid = threadIdx.x;

  // XCD-chunked bijective swizzle (2080 = 8 * 260).
  const int work = (blockIdx.x % NXCD) * (NPAIRS / NXCD) + blockIdx.x / NXCD;

  // triangular decode: work -> (ti, tj), ti <= tj
  int rem = work;
  int ti = 0;
  while (rem >= NTILES - ti) {
    rem -= NTILES - ti;
    ++ti;
  }
  const int tj = ti + rem;
  const bool diag = (ti == tj);
  const int row0 = ti * BM;
  const int m0 = tj * BM;

  if (tid < BM) {
    rowAcc[tid] = 0.0f;
    sRow[tid] = rowS[row0 + tid];
  } else {
    colAcc[tid - BM] = 0.0f;
    sCol[tid - BM] = rowS[m0 + tid - BM];
  }

  const int wave = tid >> 6, lane = tid & 63;
  const int wr = wave >> 1, wc = wave & 1;  // 2x2 wave grid, each 64x64
  const int l15 = lane & 15, l4 = lane >> 4;

  // ---- A staging geometry (R8-identical, A only) ----
  const int rs = tid >> 2;
  const int qs = tid & 3;
  const int ss = qs ^ ((rs >> 1) & 3);
  const char* gA0 = zq + (size_t)(row0 + rs) * D_DIM + ss * 16;
  const size_t dR64 = (size_t)64 * D_DIM;  // +64 rows
  const int WA0 = tid * 16;
  const int WA1 = tid * 16 + 4096;

  // ---- A fragment LDS offsets ----
  int offA[4];
#pragma unroll
  for (int mi = 0; mi < 4; ++mi) {
    const int rA = wr * 64 + mi * 16 + l15;
    offA[mi] = rA * 64 + ((l4 ^ ((rA >> 1) & 3)) << 4);
  }

  // ---- B direct-global base (per lane): row m0 + wc*64 + l15, k-chunk l4 ----
  const char* gB = zq + (size_t)(m0 + wc * 64 + l15) * D_DIM + l4 * 16;

  i32x4 acc[4][4];  // 64 regs, AGPR-backed (4-reg C/D shape)
#pragma unroll
  for (int mi = 0; mi < 4; ++mi)
#pragma unroll
    for (int ni = 0; ni < 4; ++ni) acc[mi][ni] = (i32x4){0, 0, 0, 0};

#define STAGE(kk)                                                      \
  {                                                                    \
    char* slot_ = ldsbuf + ((kk) & (RING - 1)) * SLOT_BYTES;           \
    const char* g_ = gA0 + (size_t)(kk)*BK;                            \
    load_lds_16B(g_, slot_ + WA0);                                     \
    load_lds_16B(g_ + dR64, slot_ + WA1);                              \
  }

#define COMPUTE(kk)                                                         \
  {                                                                         \
    const char* slot_ = ldsbuf + ((kk) & (RING - 1)) * SLOT_BYTES;          \
    const char* gk_ = gB + (size_t)(kk)*BK;                                 \
    i32x4 af[4], bf[4];                                                     \
    _Pragma("unroll") for (int ni = 0; ni < 4; ++ni) bf[ni] =               \
        *reinterpret_cast<const i32x4*>(gk_ + (size_t)ni * 16 * D_DIM);     \
    _Pragma("unroll") for (int mi = 0; mi < 4; ++mi)                        \
        af[mi] = *reinterpret_cast<const i32x4*>(slot_ + offA[mi]);         \
    __builtin_amdgcn_s_setprio(1);                                          \
    _Pragma("unroll") for (int mi = 0; mi < 4; ++mi)                        \
        _Pragma("unroll") for (int ni = 0; ni < 4; ++ni) acc[mi][ni] =      \
            __builtin_amdgcn_mfma_i32_16x16x64_i8(af[mi], bf[ni],           \
                                                  acc[mi][ni], 0, 0, 0);    \
    __builtin_amdgcn_s_setprio(0);                                          \
  }

  // prologue
  STAGE(0);
  VMCNT0();
  BARRIER();

  // steady state: issue next A-tile's staging, compute current, wait, barrier
  for (int k = 0; k < NT - 1; ++k) {
    STAGE(k + 1);
    COMPUTE(k);
    VMCNT0();  // STAGE(k+1) issued a full compute-phase ago; B already used
    BARRIER();
  }
  COMPUTE(NT - 1);

  // ---- diagonal extraction (PRE-exp, exact int accumulators) ----
  // ti==tj blocks: dn[row]; tj==ti+32 blocks: pos[row] (B_ROWS = 32 tiles).
  if (diag || tj == ti + 32) {
    float* dst = diag ? dn : pos;
    if (wr == wc) {
#pragma unroll
      for (int mi = 0; mi < 4; ++mi) {
#pragma unroll
        for (int j = 0; j < 4; ++j) {
          if (l15 == l4 * 4 + j) {
            const int rloc = wr * 64 + mi * 16 + l4 * 4 + j;
            dst[row0 + rloc] =
                sRow[rloc] * sCol[rloc] * (float)acc[mi][mi][j];
          }
        }
      }
    }
  }

  // ---- epilogue: scale + exp2 (in place, bitcast) + row/col reductions ----
  // C/D: col = wc*64 + ni*16 + l15, row = wr*64 + mi*16 + l4*4 + j
  const float C2 = 2.8853900817779268f;  // 2*log2(e)
  float cCol0 = C2 * sCol[wc * 64 + 0 * 16 + l15];
  float cCol1 = C2 * sCol[wc * 64 + 1 * 16 + l15];
  float cCol2 = C2 * sCol[wc * 64 + 2 * 16 + l15];
  float cCol3 = C2 * sCol[wc * 64 + 3 * 16 + l15];

#pragma unroll
  for (int mi = 0; mi < 4; ++mi) {
#pragma unroll
    for (int j = 0; j < 4; ++j) {
      const float srow = sRow[wr * 64 + mi * 16 + l4 * 4 + j];
      acc[mi][0][j] = __float_as_int(exp2f(cCol0 * srow * (float)acc[mi][0][j]));
      acc[mi][1][j] = __float_as_int(exp2f(cCol1 * srow * (float)acc[mi][1][j]));
      acc[mi][2][j] = __float_as_int(exp2f(cCol2 * srow * (float)acc[mi][2][j]));
      acc[mi][3][j] = __float_as_int(exp2f(cCol3 * srow * (float)acc[mi][3][j]));
    }
  }

  // row sums: fixed (mi, j, l4) -> sum over ni (in-lane) + l15 group
#pragma unroll
  for (int mi = 0; mi < 4; ++mi) {
#pragma unroll
    for (int j = 0; j < 4; ++j) {
      float s = __int_as_float(acc[mi][0][j]) + __int_as_float(acc[mi][1][j]) +
                __int_as_float(acc[mi][2][j]) + __int_as_float(acc[mi][3][j]);
      s += __shfl_xor(s, 1, 64);
      s += __shfl_xor(s, 2, 64);
      s += __shfl_xor(s, 4, 64);
      s += __shfl_xor(s, 8, 64);
      if (l15 == 0) atomicAdd(&rowAcc[wr * 64 + mi * 16 + l4 * 4 + j], s);
    }
  }

  // col sums (off-diagonal only): fixed (ni, l15) -> sum over mi, j + l4 group
  if (!diag) {
#pragma unroll
    for (int ni = 0; ni < 4; ++ni) {
      float s = 0.0f;
#pragma unroll
      for (int mi = 0; mi < 4; ++mi)
#pragma unroll
        for (int j = 0; j < 4; ++j) s += __int_as_float(acc[mi][ni][j]);
      s += __shfl_xor(s, 16, 64);
      s += __shfl_xor(s, 32, 64);
      if (l4 == 0) atomicAdd(&colAcc[wc * 64 + ni * 16 + l15], s);
    }
  }

  LGKM0();  // drain own ds_atomics before the barrier
  BARRIER();
  if (tid < BM) partial[(size_t)(row0 + tid) * NSLOT + tj] = rowAcc[tid];
  if (!diag && tid >= BM && tid < 2 * BM)
    partial[(size_t)(m0 + tid - BM) * NSLOT + ti] = colAcc[tid - BM];
#undef STAGE
#undef COMPUTE
}

// ---------------------------------------------------------------------------
// Kernel 3a: per-row loss, block partial sums (32 blocks x 256 threads)
// ---------------------------------------------------------------------------
__global__ void rowloss_kernel(const float* __restrict__ partial,
                               const float* __restrict__ dn,
                               const float* __restrict__ pos,
                               float* __restrict__ blockSum) {
  const int tid = threadIdx.x;
  const int n = blockIdx.x * 256 + tid;  // 0..8191
  const float C2 = 2.8853900817779268f;
  float S = 0.0f;
#pragma unroll
  for (int c = 0; c < NSLOT; ++c) S += partial[(size_t)n * NSLOT + c];
  const float den = S - exp2f(dn[n] * C2);  // remove self-similarity term
  const float p = pos[(n < B_ROWS) ? n : (n - B_ROWS)];
  float acc = -2.0f * p + logf(den);
#pragma unroll
  for (int m = 32; m; m >>= 1) acc += __shfl_xor(acc, m, 64);
  __shared__ float red[4];
  const int wave = tid >> 6, lane = tid & 63;
  if (lane == 0) red[wave] = acc;
  __syncthreads();
  if (tid == 0) blockSum[blockIdx.x] = red[0] + red[1] + red[2] + red[3];
}

// ---------------------------------------------------------------------------
// Kernel 3b: reduce 32 block sums -> scalar loss
// ---------------------------------------------------------------------------
__global__ void final2_kernel(const float* __restrict__ blockSum,
                              float* __restrict__ out) {
  const int tid = threadIdx.x;  // 64
  float v = (tid < 32) ? blockSum[tid] : 0.0f;
#pragma unroll
  for (int m = 32; m; m >>= 1) v += __shfl_xor(v, m, 64);
  if (tid == 0) out[0] = v / (float)N_ROWS;
}

// ---------------------------------------------------------------------------
extern "C" void kernel_launch(void* const* d_in, const int* in_sizes, int n_in,
                              void* d_out, int out_size, void* d_ws,
                              size_t ws_size, hipStream_t stream) {
  const float* emb_i = (const float*)d_in[0];
  const float* emb_j = (const float*)d_in[1];
  float* out = (float*)d_out;

  // workspace layout
  char* zq = (char*)d_ws;                                         // 8 MB i8
  char* p = (char*)d_ws + (size_t)N_ROWS * D_DIM;
  float* partial = (float*)p;                                     // 2 MB
  p += (size_t)N_ROWS * NSLOT * sizeof(float);
  float* dn = (float*)p;                                          // 32 KB
  p += (size_t)N_ROWS * sizeof(float);
  float* rowS = (float*)p;                                        // 32 KB
  p += (size_t)N_ROWS * sizeof(float);
  float* pos = (float*)p;                                         // 16 KB
  p += (size_t)B_ROWS * sizeof(float);
  float* blockSum = (float*)p;                                    // 128 B

  normalize_kernel<<<N_ROWS / 4, 256, 0, stream>>>(emb_i, emb_j, zq, rowS);
  simexp_kernel<<<NPAIRS, 256, 0, stream>>>(zq, rowS, partial, dn, pos);
  rowloss_kernel<<<N_ROWS / 256, 256, 0, stream>>>(partial, dn, pos, blockSum);
  final2_kernel<<<1, 64, 0, stream>>>(blockSum, out);
}

// Round 14
// 75.648 us; speedup vs baseline: 1.4283x; 1.4283x over previous
//
#include <hip/hip_runtime.h>
#include <hip/hip_bf16.h>
#include <math.h>

// Problem constants
#define B_ROWS 4096
#define N_ROWS 8192          // 2B
#define D_DIM  1024
#define NTILES 64            // 8192 / 128
#define NSLOT  64            // partial slots per row = one per "other" tile
#define NPAIRS (NTILES * (NTILES + 1) / 2)  // 2080 upper-triangle tile pairs
#define NXCD 8

#define BM 128
#define BK 64                // i8 elems per K-tile = 64 B per row
#define NT (D_DIM / BK)      // 16 K-tiles
#define SLOT_BYTES 16384     // A (8 KB) + B (8 KB) per ring slot
#define RING 2               // double buffer: 32 KB -> 4 blocks/CU (R8-proven)

typedef __attribute__((ext_vector_type(4))) int i32x4;

__device__ __forceinline__ void load_lds_16B(const void* g, void* l) {
  __builtin_amdgcn_global_load_lds(
      (const __attribute__((address_space(1))) void*)g,
      (__attribute__((address_space(3))) void*)l, 16, 0, 0);
}

#define VMCNT0() asm volatile("s_waitcnt vmcnt(0)" ::: "memory")
#define LGKM0()  asm volatile("s_waitcnt lgkmcnt(0)" ::: "memory")
#define BARRIER() asm volatile("s_barrier" ::: "memory")

// ---------------------------------------------------------------------------
// Kernel 1: wave-per-row L2-normalize + symmetric int8 quantization.
// No __syncthreads, no LDS: 4 waves/block, each wave owns one row.
// zq[n][d] = rint(z*127/max|z|), rowS[n] = max|z|/127.
// (dn and pos are produced by simexp's diagonal extraction.)
// ---------------------------------------------------------------------------
__global__ __launch_bounds__(256) void normalize_kernel(
    const float* __restrict__ emb_i, const float* __restrict__ emb_j,
    char* __restrict__ zq, float* __restrict__ rowS) {
  const int lane = threadIdx.x & 63;
  const int wave = threadIdx.x >> 6;
  const int row = blockIdx.x * 4 + wave;
  const float* src = (row < B_ROWS) ? (emb_i + (size_t)row * D_DIM)
                                    : (emb_j + (size_t)(row - B_ROWS) * D_DIM);
  const float4* s4 = reinterpret_cast<const float4*>(src);
  float4 v0 = s4[lane], v1 = s4[lane + 64], v2 = s4[lane + 128],
         v3 = s4[lane + 192];

  float ss = v0.x * v0.x + v0.y * v0.y + v0.z * v0.z + v0.w * v0.w +
             v1.x * v1.x + v1.y * v1.y + v1.z * v1.z + v1.w * v1.w +
             v2.x * v2.x + v2.y * v2.y + v2.z * v2.z + v2.w * v2.w +
             v3.x * v3.x + v3.y * v3.y + v3.z * v3.z + v3.w * v3.w;
#pragma unroll
  for (int m = 32; m; m >>= 1) ss += __shfl_xor(ss, m, 64);
  const float scale = 1.0f / fmaxf(sqrtf(ss), 1e-12f);

  float z[16];
  z[0] = v0.x * scale;  z[1] = v0.y * scale;  z[2] = v0.z * scale;
  z[3] = v0.w * scale;  z[4] = v1.x * scale;  z[5] = v1.y * scale;
  z[6] = v1.z * scale;  z[7] = v1.w * scale;  z[8] = v2.x * scale;
  z[9] = v2.y * scale;  z[10] = v2.z * scale; z[11] = v2.w * scale;
  z[12] = v3.x * scale; z[13] = v3.y * scale; z[14] = v3.z * scale;
  z[15] = v3.w * scale;

  float am = 0.0f;
#pragma unroll
  for (int i = 0; i < 16; ++i) am = fmaxf(am, fabsf(z[i]));
#pragma unroll
  for (int m = 32; m; m >>= 1) am = fmaxf(am, __shfl_xor(am, m, 64));
  const float s = am * (1.0f / 127.0f);
  const float inv = (am > 0.0f) ? 127.0f / am : 0.0f;

  char4* dst = reinterpret_cast<char4*>(zq + (size_t)row * D_DIM);
#pragma unroll
  for (int i = 0; i < 4; ++i) {
    char4 pk;
    pk.x = (char)(int)rintf(z[i * 4 + 0] * inv);
    pk.y = (char)(int)rintf(z[i * 4 + 1] * inv);
    pk.z = (char)(int)rintf(z[i * 4 + 2] * inv);
    pk.w = (char)(int)rintf(z[i * 4 + 3] * inv);
    dst[lane + 64 * i] = pk;
  }
  if (lane == 0) rowS[row] = s;
}

// ---------------------------------------------------------------------------
// Kernel 2: fused i8 GEMM + scale + exp + row/col-sum, symmetric tile pairs.
// R8-proven ring-2 2-phase schedule (STAGE(k+1) before COMPUTE(k), single
// vmcnt(0)+barrier per K-tile, 32 KB LDS -> 4 blocks/CU).
// MFMA = mfma_i32_16x16x64_i8 (4-reg C/D -> AGPR-allocated; 16-reg C/D
// spills on this toolchain -- R5/R6/R7 lesson).
// Diagonal extraction (pre-exp): ti==tj blocks write dn[] (exact self-sim);
// tj==ti+32 blocks write pos[] (the positives diagonal).
//
// Structural optimum (R9/R11/R12 all regressed): at this tile shape the
// kernel co-saturates MFMA (~22%), VALU (~27%) and LDS issue; wider wave
// tiles are blocked by the 4-reg-C/D AGPR constraint, deeper pipelines by
// the 4-blocks/CU occupancy requirement, B-from-global by coalescing.
//
// LDS per ring slot (16 KB): A[128][64B] at +0, B[128][64B] at +8192.
// Row r: 4 16-B slots; logical slot s at physical s ^ ((r>>1)&3)
// (pre-swizzled global source + swizzled ds_read; measured 0 conflicts).
// C/D layout (16x16, dtype-independent): col = lane&15, row = (l>>4)*4 + reg.
// ---------------------------------------------------------------------------
__global__ __launch_bounds__(256, 4) void simexp_kernel(
    const char* __restrict__ zq, const float* __restrict__ rowS,
    float* __restrict__ partial, float* __restrict__ dn,
    float* __restrict__ pos) {
  __shared__ __align__(16) char ldsbuf[RING * SLOT_BYTES];  // 32 KB
  __shared__ float rowAcc[BM];
  __shared__ float colAcc[BM];
  __shared__ float sRow[BM];
  __shared__ float sCol[BM];

  const int tid = threadIdx.x;

  // XCD-chunked bijective swizzle (2080 = 8 * 260).
  const int work = (blockIdx.x % NXCD) * (NPAIRS / NXCD) + blockIdx.x / NXCD;

  // triangular decode: work -> (ti, tj), ti <= tj
  int rem = work;
  int ti = 0;
  while (rem >= NTILES - ti) {
    rem -= NTILES - ti;
    ++ti;
  }
  const int tj = ti + rem;
  const bool diag = (ti == tj);
  const int row0 = ti * BM;
  const int m0 = tj * BM;

  if (tid < BM) {
    rowAcc[tid] = 0.0f;
    sRow[tid] = rowS[row0 + tid];
  } else {
    colAcc[tid - BM] = 0.0f;
    sCol[tid - BM] = rowS[m0 + tid - BM];
  }

  const int wave = tid >> 6, lane = tid & 63;
  const int wr = wave >> 1, wc = wave & 1;  // 2x2 wave grid, each 64x64
  const int l15 = lane & 15, l4 = lane >> 4;

  // ---- staging geometry: one per-lane base + uniform deltas ----
  const int rs = tid >> 2;
  const int qs = tid & 3;
  const int ss = qs ^ ((rs >> 1) & 3);
  const char* gA0 = zq + (size_t)(row0 + rs) * D_DIM + ss * 16;
  const size_t dR64 = (size_t)64 * D_DIM;         // +64 rows
  const size_t dB = (size_t)(m0 - row0) * D_DIM;  // A-panel -> B-panel
  const int WA0 = tid * 16;
  const int WA1 = tid * 16 + 4096;

  // ---- fragment read offsets ----
  // frag mi: row r = wr*64 + mi*16 + l15; 16-B slot = l4 ^ ((r>>1)&3)
  int offA[4], offB[4];
#pragma unroll
  for (int mi = 0; mi < 4; ++mi) {
    const int rA = wr * 64 + mi * 16 + l15;
    offA[mi] = rA * 64 + ((l4 ^ ((rA >> 1) & 3)) << 4);
    const int rB = wc * 64 + mi * 16 + l15;
    offB[mi] = 8192 + rB * 64 + ((l4 ^ ((rB >> 1) & 3)) << 4);
  }

  i32x4 acc[4][4];  // 64 regs, AGPR-backed (4-reg C/D shape)
#pragma unroll
  for (int mi = 0; mi < 4; ++mi)
#pragma unroll
    for (int ni = 0; ni < 4; ++ni) acc[mi][ni] = (i32x4){0, 0, 0, 0};

#define STAGE(kk)                                                      \
  {                                                                    \
    char* slot_ = ldsbuf + ((kk) & (RING - 1)) * SLOT_BYTES;           \
    const char* g_ = gA0 + (size_t)(kk)*BK;                            \
    load_lds_16B(g_, slot_ + WA0);                                     \
    load_lds_16B(g_ + dR64, slot_ + WA1);                              \
    load_lds_16B(g_ + dB, slot_ + 8192 + WA0);                         \
    load_lds_16B(g_ + dB + dR64, slot_ + 8192 + WA1);                  \
  }

#define COMPUTE(kk)                                                    \
  {                                                                    \
    const char* slot_ = ldsbuf + ((kk) & (RING - 1)) * SLOT_BYTES;     \
    i32x4 af[4], bf[4];                                                \
    _Pragma("unroll") for (int mi = 0; mi < 4; ++mi)                   \
        af[mi] = *reinterpret_cast<const i32x4*>(slot_ + offA[mi]);    \
    _Pragma("unroll") for (int ni = 0; ni < 4; ++ni)                   \
        bf[ni] = *reinterpret_cast<const i32x4*>(slot_ + offB[ni]);    \
    __builtin_amdgcn_s_setprio(1);                                     \
    _Pragma("unroll") for (int mi = 0; mi < 4; ++mi)                   \
        _Pragma("unroll") for (int ni = 0; ni < 4; ++ni) acc[mi][ni] = \
            __builtin_amdgcn_mfma_i32_16x16x64_i8(af[mi], bf[ni],      \
                                                  acc[mi][ni], 0, 0,   \
                                                  0);                  \
    __builtin_amdgcn_s_setprio(0);                                     \
  }

  // prologue
  STAGE(0);
  VMCNT0();
  BARRIER();

  // steady state: issue next tile's loads, compute current, wait, barrier
  for (int k = 0; k < NT - 1; ++k) {
    STAGE(k + 1);
    COMPUTE(k);
    VMCNT0();  // STAGE(k+1) was issued a full compute-phase ago
    BARRIER();
  }
  COMPUTE(NT - 1);

  // ---- diagonal extraction (PRE-exp, exact int accumulators) ----
  // In-tile diagonal element (t,t): needs wr==wc, ni==mi, l15 == l4*4+j.
  // ti==tj blocks: dn[row]; tj==ti+32: pos[row] (B_ROWS = 32 tiles).
  if (diag || tj == ti + 32) {
    float* dst = diag ? dn : pos;
    if (wr == wc) {
#pragma unroll
      for (int mi = 0; mi < 4; ++mi) {
#pragma unroll
        for (int j = 0; j < 4; ++j) {
          if (l15 == l4 * 4 + j) {
            const int rloc = wr * 64 + mi * 16 + l4 * 4 + j;
            dst[row0 + rloc] =
                sRow[rloc] * sCol[rloc] * (float)acc[mi][mi][j];
          }
        }
      }
    }
  }

  // ---- epilogue: scale + exp2 (in place, bitcast) + row/col reductions ----
  // sim(row,col) = sRow[row]*sCol[col]*acc; exp(2*sim) = exp2(C2*sim)
  // C/D: col = wc*64 + ni*16 + l15, row = wr*64 + mi*16 + l4*4 + j
  const float C2 = 2.8853900817779268f;  // 2*log2(e)
  float cCol0 = C2 * sCol[wc * 64 + 0 * 16 + l15];
  float cCol1 = C2 * sCol[wc * 64 + 1 * 16 + l15];
  float cCol2 = C2 * sCol[wc * 64 + 2 * 16 + l15];
  float cCol3 = C2 * sCol[wc * 64 + 3 * 16 + l15];

#pragma unroll
  for (int mi = 0; mi < 4; ++mi) {
#pragma unroll
    for (int j = 0; j < 4; ++j) {
      const float srow = sRow[wr * 64 + mi * 16 + l4 * 4 + j];
      acc[mi][0][j] = __float_as_int(exp2f(cCol0 * srow * (float)acc[mi][0][j]));
      acc[mi][1][j] = __float_as_int(exp2f(cCol1 * srow * (float)acc[mi][1][j]));
      acc[mi][2][j] = __float_as_int(exp2f(cCol2 * srow * (float)acc[mi][2][j]));
      acc[mi][3][j] = __float_as_int(exp2f(cCol3 * srow * (float)acc[mi][3][j]));
    }
  }

  // row sums: fixed (mi, j, l4) -> sum over ni (in-lane) + l15 group
#pragma unroll
  for (int mi = 0; mi < 4; ++mi) {
#pragma unroll
    for (int j = 0; j < 4; ++j) {
      float s = __int_as_float(acc[mi][0][j]) + __int_as_float(acc[mi][1][j]) +
                __int_as_float(acc[mi][2][j]) + __int_as_float(acc[mi][3][j]);
      s += __shfl_xor(s, 1, 64);
      s += __shfl_xor(s, 2, 64);
      s += __shfl_xor(s, 4, 64);
      s += __shfl_xor(s, 8, 64);
      if (l15 == 0) atomicAdd(&rowAcc[wr * 64 + mi * 16 + l4 * 4 + j], s);
    }
  }

  // col sums (off-diagonal only): fixed (ni, l15) -> sum over mi, j + l4 group
  if (!diag) {
#pragma unroll
    for (int ni = 0; ni < 4; ++ni) {
      float s = 0.0f;
#pragma unroll
      for (int mi = 0; mi < 4; ++mi)
#pragma unroll
        for (int j = 0; j < 4; ++j) s += __int_as_float(acc[mi][ni][j]);
      s += __shfl_xor(s, 16, 64);
      s += __shfl_xor(s, 32, 64);
      if (l4 == 0) atomicAdd(&colAcc[wc * 64 + ni * 16 + l15], s);
    }
  }

  LGKM0();  // drain own ds_atomics before the barrier
  BARRIER();
  if (tid < BM) partial[(size_t)(row0 + tid) * NSLOT + tj] = rowAcc[tid];
  if (!diag && tid >= BM && tid < 2 * BM)
    partial[(size_t)(m0 + tid - BM) * NSLOT + ti] = colAcc[tid - BM];
#undef STAGE
#undef COMPUTE
}

// ---------------------------------------------------------------------------
// Kernel 3a: per-row loss, block partial sums (32 blocks x 256 threads)
// ---------------------------------------------------------------------------
__global__ void rowloss_kernel(const float* __restrict__ partial,
                               const float* __restrict__ dn,
                               const float* __restrict__ pos,
                               float* __restrict__ blockSum) {
  const int tid = threadIdx.x;
  const int n = blockIdx.x * 256 + tid;  // 0..8191
  const float C2 = 2.8853900817779268f;
  float S = 0.0f;
#pragma unroll
  for (int c = 0; c < NSLOT; ++c) S += partial[(size_t)n * NSLOT + c];
  const float den = S - exp2f(dn[n] * C2);  // remove self-similarity term
  const float p = pos[(n < B_ROWS) ? n : (n - B_ROWS)];
  float acc = -2.0f * p + logf(den);
#pragma unroll
  for (int m = 32; m; m >>= 1) acc += __shfl_xor(acc, m, 64);
  __shared__ float red[4];
  const int wave = tid >> 6, lane = tid & 63;
  if (lane == 0) red[wave] = acc;
  __syncthreads();
  if (tid == 0) blockSum[blockIdx.x] = red[0] + red[1] + red[2] + red[3];
}

// ---------------------------------------------------------------------------
// Kernel 3b: reduce 32 block sums -> scalar loss
// ---------------------------------------------------------------------------
__global__ void final2_kernel(const float* __restrict__ blockSum,
                              float* __restrict__ out) {
  const int tid = threadIdx.x;  // 64
  float v = (tid < 32) ? blockSum[tid] : 0.0f;
#pragma unroll
  for (int m = 32; m; m >>= 1) v += __shfl_xor(v, m, 64);
  if (tid == 0) out[0] = v / (float)N_ROWS;
}

// ---------------------------------------------------------------------------
extern "C" void kernel_launch(void* const* d_in, const int* in_sizes, int n_in,
                              void* d_out, int out_size, void* d_ws,
                              size_t ws_size, hipStream_t stream) {
  const float* emb_i = (const float*)d_in[0];
  const float* emb_j = (const float*)d_in[1];
  float* out = (float*)d_out;

  // workspace layout
  char* zq = (char*)d_ws;                                         // 8 MB i8
  char* p = (char*)d_ws + (size_t)N_ROWS * D_DIM;
  float* partial = (float*)p;                                     // 2 MB
  p += (size_t)N_ROWS * NSLOT * sizeof(float);
  float* dn = (float*)p;                                          // 32 KB
  p += (size_t)N_ROWS * sizeof(float);
  float* rowS = (float*)p;                                        // 32 KB
  p += (size_t)N_ROWS * sizeof(float);
  float* pos = (float*)p;                                         // 16 KB
  p += (size_t)B_ROWS * sizeof(float);
  float* blockSum = (float*)p;                                    // 128 B

  normalize_kernel<<<N_ROWS / 4, 256, 0, stream>>>(emb_i, emb_j, zq, rowS);
  simexp_kernel<<<NPAIRS, 256, 0, stream>>>(zq, rowS, partial, dn, pos);
  rowloss_kernel<<<N_ROWS / 256, 256, 0, stream>>>(partial, dn, pos, blockSum);
  final2_kernel<<<1, 64, 0, stream>>>(blockSum, out);
}